// Round 1
// baseline (24.461 us; speedup 1.0000x reference)
//
#include <hip/hip_runtime.h>
#include <math.h>

#define KACC 10

__global__ __launch_bounds__(256)
void sss_kernel(const float* __restrict__ Z, const float* __restrict__ U,
                const float* __restrict__ uu, const float* __restrict__ ga,
                const float* __restrict__ la, float* __restrict__ out,
                int P, int B, int K)
{
#pragma clang fp contract(off)
    int p = blockIdx.x * blockDim.x + threadIdx.x;
    if (p >= P) return;

    const float g      = ga[p];
    const float lalpha = la[p];

    // --- MarsagliaTsampler per-column constants ---
    const float alpha = fmaxf(g, 0.0f) + 1.0f;     // relu + 1
    const float d     = alpha - (1.0f / 3.0f);
    const float c     = 1.0f / sqrtf(9.0f * d);
    const float neg_inv_c = -(1.0f / c);

    // --- rejection scan: first K accepted samples down the rows ---
    float th[KACC];
#pragma unroll
    for (int k = 0; k < KACC; ++k) th[k] = 0.0f;

    int cnt = 0;
    for (int b = 0; b < B; ++b) {
        const size_t off = (size_t)b * (size_t)P + (size_t)p;
        float z  = Z[off];
        float Uv = U[off];
        float t  = 1.0f + c * z;
        float V  = (t * t) * t;                    // (1+cZ)**3, same assoc as npy_pow
        bool  c1 = z > neg_inv_c;
        // ((0.5*Z^2 + d) - d*V) + d*log(V); log(V<=0) -> NaN/-inf -> cond2 false
        float rhs = ((0.5f * (z * z) + d) - d * V) + d * logf(V);
        bool  c2 = logf(Uv) < rhs;                 // NaN rhs compares false
        if (c1 && c2) {
            th[cnt] = d * V;
            cnt++;
            if (cnt == KACC) break;
        }
    }

    // --- output layout: z[K,P], z_mean[P], theta[K,P], alpha[P], logalpha[P] ---
    const size_t KP = (size_t)K * (size_t)P;
    float* o_z        = out;
    float* o_zmean    = out + KP;
    float* o_theta    = out + KP + (size_t)P;
    float* o_alpha    = out + 2 * KP + (size_t)P;
    float* o_logalpha = out + 2 * KP + 2 * (size_t)P;

#pragma unroll
    for (int k = 0; k < KACC; ++k)
        o_theta[(size_t)k * (size_t)P + (size_t)p] = th[k];

    // --- hard-concrete gate ---
    // z_mean = sigmoid(logalpha - BETA * GZ_LOGRATIO)
    const float SHIFT = (float)(2.0 / 3.0 * (0.1 / 1.1)); // 0.060606062f
    float xm = lalpha - SHIFT;
    float zm = 1.0f / (1.0f + expf(-xm));

#pragma unroll
    for (int k = 0; k < KACC; ++k) {
        float uv = uu[(size_t)k * (size_t)P + (size_t)p];
        // s = sigmoid((log(u) - log1p(-u) + logalpha) / BETA)
        float x = ((logf(uv) - log1pf(-uv)) + lalpha) / (2.0f / 3.0f);
        float s = 1.0f / (1.0f + expf(-x));
        // z = clip((ZETA-GAMMA)*s + GAMMA, 0, 1) = clip(1.2*s - 0.1, 0, 1)
        float zz = 1.2f * s + (-0.1f);
        zz = fminf(fmaxf(zz, 0.0f), 1.0f);
        o_z[(size_t)k * (size_t)P + (size_t)p] = zz;
    }

    o_zmean[p]    = zm;
    o_alpha[p]    = alpha;
    o_logalpha[p] = lalpha;
}

extern "C" void kernel_launch(void* const* d_in, const int* in_sizes, int n_in,
                              void* d_out, int out_size, void* d_ws, size_t ws_size,
                              hipStream_t stream) {
    const float* Z  = (const float*)d_in[0];
    const float* U  = (const float*)d_in[1];
    const float* uu = (const float*)d_in[2];
    const float* ga = (const float*)d_in[3];
    const float* la = (const float*)d_in[4];
    float* out = (float*)d_out;

    const int P = in_sizes[3];            // gamma_alpha is [P]
    const int B = in_sizes[0] / P;        // Z is [B,P]
    const int K = in_sizes[2] / P;        // u is [K,P]

    const int block = 256;
    const int grid  = (P + block - 1) / block;
    sss_kernel<<<grid, block, 0, stream>>>(Z, U, uu, ga, la, out, P, B, K);
}